// Round 5
// baseline (424.738 us; speedup 1.0000x reference)
//
#include <hip/hip_runtime.h>

// SIR RK4 trajectory: 500000 rows × 3 states × 50 timesteps, f32.
// Reference quirks replicated exactly:
//   - _sir_eq returns the NEW STATE (x + f(x)), not the derivative.
//   - new = x_ORIGINAL + STEP/6*(k1+2k2+2k3+k4)  (closure over x, not prev).
// Output layout: out[row*150 + t*3 + c]  (transpose of (50,B,3) -> (B,50,3)).

#define BATCH   500000
#define NT      50
#define TCH     10          // timesteps per LDS chunk (must be even for 8B-aligned writes)
#define NCHUNK  (NT / TCH)  // 5
#define BLOCK   256

struct F3 { float s, i, r; };

__device__ __forceinline__ F3 sir_eq(F3 v, float b, float g, float rn) {
    // inf = b*S*I/n  (rn = 1/n precomputed), rec = g*I
    float inf = b * v.s * v.i * rn;
    float rec = g * v.i;
    F3 o;
    o.s = v.s - inf;
    o.i = v.i + inf - rec;
    o.r = v.r + rec;
    return o;
}

__device__ __forceinline__ F3 rk_step(F3 prev, F3 x0, float b, float g) {
    // _sir_eq preserves the component sum, so the four divisor sums are
    // n * {1, 1.05, 1.0525, 1.10525} -> 1 rcp + 3 muls (rel err ~1e-7,
    // threshold is 2.6e-2).
    float n  = prev.s + prev.i + prev.r;
    float r1 = __builtin_amdgcn_rcpf(n);
    float r2 = r1 * 0.952380952f;  // 1/1.05
    float r3 = r1 * 0.950118765f;  // 1/1.0525
    float r4 = r1 * 0.904772676f;  // 1/1.10525

    F3 k1 = sir_eq(prev, b, g, r1);
    F3 a2 = { fmaf(0.05f, k1.s, prev.s), fmaf(0.05f, k1.i, prev.i), fmaf(0.05f, k1.r, prev.r) };
    F3 k2 = sir_eq(a2, b, g, r2);
    F3 a3 = { fmaf(0.05f, k2.s, prev.s), fmaf(0.05f, k2.i, prev.i), fmaf(0.05f, k2.r, prev.r) };
    F3 k3 = sir_eq(a3, b, g, r3);
    F3 a4 = { fmaf(0.10f, k3.s, prev.s), fmaf(0.10f, k3.i, prev.i), fmaf(0.10f, k3.r, prev.r) };
    F3 k4 = sir_eq(a4, b, g, r4);

    const float C = (float)(0.1 / 6.0);
    F3 nw;
    nw.s = fmaf(C, (k1.s + k4.s) + 2.0f * (k2.s + k3.s), x0.s);
    nw.i = fmaf(C, (k1.i + k4.i) + 2.0f * (k2.i + k3.i), x0.i);
    nw.r = fmaf(C, (k1.r + k4.r) + 2.0f * (k2.r + k3.r), x0.r);
    return nw;
}

__global__ __launch_bounds__(BLOCK) void sir_rk4_kernel(
        const float* __restrict__ x,
        const float* __restrict__ beta,
        const float* __restrict__ gamma,
        float* __restrict__ out) {
    // LDS: [BLOCK threads][TCH*3 floats], no pad. Staging writes are 4-way
    // bank-aliased (stride 30) but that's ~5% of instrs. Read side collapses
    // to a perfectly linear float2 stream: l2[li], li = row*15 + g.
    __shared__ float lds[BLOCK * TCH * 3];   // 30 KiB -> 5 blocks/CU by LDS

    const int tid  = threadIdx.x;
    const int row0 = blockIdx.x * BLOCK;
    const int row  = row0 + tid;
    const int nrows = min(BLOCK, BATCH - row0);
    const bool active = tid < nrows;

    const float b = beta[0];
    const float g = gamma[0];

    F3 xv = { 1.0f, 1.0f, 1.0f };            // benign value for tail lanes
    if (active) {
        xv.s = x[(size_t)row * 3 + 0];
        xv.i = x[(size_t)row * 3 + 1];
        xv.r = x[(size_t)row * 3 + 2];
    }
    F3 prev = xv;

    for (int c = 0; c < NCHUNK; ++c) {
        // ---- compute TCH states into LDS ----
        if (c > 0) prev = rk_step(prev, xv, b, g);   // state for t = c*TCH
        lds[tid * (TCH * 3) + 0] = prev.s;
        lds[tid * (TCH * 3) + 1] = prev.i;
        lds[tid * (TCH * 3) + 2] = prev.r;
        #pragma unroll
        for (int tt = 1; tt < TCH; ++tt) {
            prev = rk_step(prev, xv, b, g);
            lds[tid * (TCH * 3) + tt * 3 + 0] = prev.s;
            lds[tid * (TCH * 3) + tt * 3 + 1] = prev.i;
            lds[tid * (TCH * 3) + tt * 3 + 2] = prev.r;
        }
        __syncthreads();

        // ---- cooperative coalesced write: nrows * 15 float2 (8B aligned:
        //      row*600 + c*120 + g*8, all multiples of 8) ----
        const float2* l2 = (const float2*)lds;
        const int total = nrows * (TCH * 3 / 2);   // nrows * 15
        #pragma unroll
        for (int it = 0; it < TCH * 3 / 2; ++it) { // 15 iterations
            int li = it * BLOCK + tid;
            if (li < total) {
                int r  = li / 15;
                int gg = li - r * 15;
                float2 v = l2[li];                 // lds float offset = 2*li exactly
                *reinterpret_cast<float2*>(
                    out + (size_t)(row0 + r) * (NT * 3) + c * (TCH * 3) + 2 * gg) = v;
            }
        }
        __syncthreads();
    }
}

extern "C" void kernel_launch(void* const* d_in, const int* in_sizes, int n_in,
                              void* d_out, int out_size, void* d_ws, size_t ws_size,
                              hipStream_t stream) {
    const float* x     = (const float*)d_in[0];
    const float* beta  = (const float*)d_in[1];
    const float* gamma = (const float*)d_in[2];
    float* out = (float*)d_out;

    const int grid = (BATCH + BLOCK - 1) / BLOCK;   // 1954
    sir_rk4_kernel<<<grid, BLOCK, 0, stream>>>(x, beta, gamma, out);
}

// Round 6
// 339.257 us; speedup vs baseline: 1.2520x; 1.2520x over previous
//
#include <hip/hip_runtime.h>

// SIR RK4 trajectory: 500000 rows × 3 states × 50 timesteps, f32.
// Reference quirks replicated exactly:
//   - _sir_eq returns the NEW STATE (x + f(x)), not the derivative.
//   - new = x_ORIGINAL + STEP/6*(k1+2k2+2k3+k4)  (closure over x, not prev).
// Output layout: out[row*150 + t*3 + c].
//
// Structure (round 6): full-trajectory LDS staging.
//   block = 64 threads = 1 wave, 1 row/thread, LDS = 64 rows × 600 B = 37.5 KiB
//   -> 4 blocks/CU. Block's output region is contiguous + 256B-aligned
//   (64*600 = 38400 B), emitted as linear float4 stores: every HBM line is
//   written exactly once, fully (kills the partial-line/masked-sector cost the
//   chunked TCH=10 scheme paid: 120B islands at 8B alignment -> ~65% write
//   efficiency -> ~180us kernel. Floor is 300MB / ~4.9TB/s pure-write ~ 61us).
//   Single wave -> no __syncthreads needed for LDS ordering (lgkmcnt covers it).

#define BATCH 500000
#define NT    50
#define NF    (NT * 3)   // 150 floats per row
#define ROWS  64         // rows per block == threads per block (1 wave)

struct F3 { float s, i, r; };

__device__ __forceinline__ F3 sir_eq(F3 v, float b, float g, float rn) {
    // inf = b*S*I/n  (rn = 1/n precomputed), rec = g*I
    float inf = b * v.s * v.i * rn;
    float rec = g * v.i;
    F3 o;
    o.s = v.s - inf;
    o.i = v.i + inf - rec;
    o.r = v.r + rec;
    return o;
}

__device__ __forceinline__ F3 rk_step(F3 prev, F3 x0, float b, float g) {
    // _sir_eq preserves the component sum, so the four divisor sums are
    // n * {1, 1.05, 1.0525, 1.10525} -> 1 rcp + 3 muls (rel err ~1e-7;
    // measured absmax 0.0078 vs threshold 0.0259).
    float n  = prev.s + prev.i + prev.r;
    float r1 = __builtin_amdgcn_rcpf(n);
    float r2 = r1 * 0.952380952f;  // 1/1.05
    float r3 = r1 * 0.950118765f;  // 1/1.0525
    float r4 = r1 * 0.904772676f;  // 1/1.10525

    F3 k1 = sir_eq(prev, b, g, r1);
    F3 a2 = { fmaf(0.05f, k1.s, prev.s), fmaf(0.05f, k1.i, prev.i), fmaf(0.05f, k1.r, prev.r) };
    F3 k2 = sir_eq(a2, b, g, r2);
    F3 a3 = { fmaf(0.05f, k2.s, prev.s), fmaf(0.05f, k2.i, prev.i), fmaf(0.05f, k2.r, prev.r) };
    F3 k3 = sir_eq(a3, b, g, r3);
    F3 a4 = { fmaf(0.10f, k3.s, prev.s), fmaf(0.10f, k3.i, prev.i), fmaf(0.10f, k3.r, prev.r) };
    F3 k4 = sir_eq(a4, b, g, r4);

    const float C = (float)(0.1 / 6.0);
    F3 nw;
    nw.s = fmaf(C, (k1.s + k4.s) + 2.0f * (k2.s + k3.s), x0.s);
    nw.i = fmaf(C, (k1.i + k4.i) + 2.0f * (k2.i + k3.i), x0.i);
    nw.r = fmaf(C, (k1.r + k4.r) + 2.0f * (k2.r + k3.r), x0.r);
    return nw;
}

__global__ __launch_bounds__(ROWS) void sir_rk4_kernel(
        const float* __restrict__ x,
        const float* __restrict__ beta,
        const float* __restrict__ gamma,
        float* __restrict__ out) {
    // Row-major [64][150] f32, no pad. Compute-side ds_writes are 4-way
    // bank-aliased (stride 150 % 32 banks) — ~1.3k cyc/block, hidden under
    // the write phase. Read-out side is dense b128, conflict-free.
    __shared__ __align__(16) float lds[ROWS * NF];   // 38400 B -> 4 blocks/CU

    const int lane  = threadIdx.x;
    const int row0  = blockIdx.x * ROWS;
    const int row   = row0 + lane;
    const int nrows = min(ROWS, BATCH - row0);
    const bool active = lane < nrows;

    const float b = beta[0];
    const float g = gamma[0];

    F3 xv = { 1.0f, 1.0f, 1.0f };                    // benign value for tail lanes
    if (active) {
        xv.s = x[(size_t)row * 3 + 0];
        xv.i = x[(size_t)row * 3 + 1];
        xv.r = x[(size_t)row * 3 + 2];
    }

    float* myrow = lds + lane * NF;
    myrow[0] = xv.s; myrow[1] = xv.i; myrow[2] = xv.r;   // t = 0 is x itself

    F3 prev = xv;
    for (int s = 1; s < NT; ++s) {
        prev = rk_step(prev, xv, b, g);
        myrow[s * 3 + 0] = prev.s;
        myrow[s * 3 + 1] = prev.i;
        myrow[s * 3 + 2] = prev.r;
    }

    __syncthreads();   // 1 wave: compiles to lgkmcnt drain; cheap safety

    // ---- linear, fully-coalesced write-out: nrows*600 B contiguous,
    //      block base = row0*600 = 38400*bid -> 256B-aligned ----
    const float4* l4 = (const float4*)lds;
    float4* o4 = reinterpret_cast<float4*>(out + (size_t)row0 * NF);
    const int total4 = nrows * NF / 4;               // 2400 (full) / 1200 (tail)
    for (int li = lane; li < total4; li += ROWS) {
        o4[li] = l4[li];
    }
}

extern "C" void kernel_launch(void* const* d_in, const int* in_sizes, int n_in,
                              void* d_out, int out_size, void* d_ws, size_t ws_size,
                              hipStream_t stream) {
    const float* x     = (const float*)d_in[0];
    const float* beta  = (const float*)d_in[1];
    const float* gamma = (const float*)d_in[2];
    float* out = (float*)d_out;

    const int grid = (BATCH + ROWS - 1) / ROWS;      // 7813
    sir_rk4_kernel<<<grid, ROWS, 0, stream>>>(x, beta, gamma, out);
}